// Round 7
// baseline (338.963 us; speedup 1.0000x reference)
//
#include <hip/hip_runtime.h>
#include <hip/hip_bf16.h>
#include <math.h>

#define SQ 2048      // seq len
#define DE 512       // d_embedding
#define DH 64        // d_head
#define CW 128       // half-window
#define W2 256       // window width
#define NH 8         // heads
#define NQ 4         // queries per block
#define UW (W2 + NQ - 1)  // union window width = 259
#define NT 512       // threads per block
#define NW 8         // waves per block

typedef __hip_bfloat16 bf16;

__device__ __forceinline__ float ld(const float* p) { return *p; }
__device__ __forceinline__ float ld(const bf16* p) { return __bfloat162float(*p); }

// prep: bf16 WTb[h][e][c], VTb[h][c][e] for all heads; fp32 copies for head 0.
__global__ __launch_bounds__(256) void prep_kernel(
    const float* __restrict__ Wq, const float* __restrict__ Wk,
    const float* __restrict__ Wvd, const float* __restrict__ Wvu,
    bf16* __restrict__ WTbq, bf16* __restrict__ WTbk, bf16* __restrict__ WTbv,
    bf16* __restrict__ VTb,
    float* __restrict__ WT0q, float* __restrict__ WT0k, float* __restrict__ WT0v,
    float* __restrict__ VT0) {
  int i = blockIdx.x * 256 + threadIdx.x;
  if (i < NH * DE * DH) {
    int c = i & 63;
    int e = (i >> 6) & 511;
    int h = i >> 15;
    int src = (h * DH + c) * DE + e;
    float wq = Wq[src], wk = Wk[src], wv = Wvd[src];
    float vu = Wvu[(h * DE + e) * DH + c];
    WTbq[i] = __float2bfloat16(wq);
    WTbk[i] = __float2bfloat16(wk);
    WTbv[i] = __float2bfloat16(wv);
    VTb[(h * DH + c) * DE + e] = __float2bfloat16(vu);
    if (h == 0) {  // i == e*DH+c here
      WT0q[i] = wq; WT0k[i] = wk; WT0v[i] = wv;
      VT0[c * DE + e] = vu;
    }
  }
}

// qkv0: x -> cur copy + fp32 q/kT/v for head 0 (head 0 must stay fp32: m1~N(0,0.045))
__global__ __launch_bounds__(NT) void qkv0_kernel(
    const float* __restrict__ x,
    const float* __restrict__ WTq, const float* __restrict__ WTk,
    const float* __restrict__ WTv, float* __restrict__ cur,
    float* __restrict__ q, float* __restrict__ kT, float* __restrict__ v) {
  __shared__ float xL[NQ][DE];            // 8 KB
  __shared__ float qP[NW][3][NQ][DH];     // 24 KB
  int tid = threadIdx.x, lane = tid & 63, wv = tid >> 6;
  int j0 = blockIdx.x * NQ;

  float4 xv = ((const float4*)(x + (size_t)j0 * DE))[tid];
  ((float4*)xL)[tid] = xv;
  ((float4*)(cur + (size_t)j0 * DE))[tid] = xv;
  __syncthreads();

  float aq[NQ] = {0, 0, 0, 0}, ak[NQ] = {0, 0, 0, 0}, av[NQ] = {0, 0, 0, 0};
  int e0 = wv * 64;
#pragma unroll
  for (int i4 = 0; i4 < 16; i4++) {
    float wq[4], wk[4], wvv[4];
#pragma unroll
    for (int u = 0; u < 4; u++) {
      int e = e0 + i4 * 4 + u;
      wq[u] = WTq[e * DH + lane];
      wk[u] = WTk[e * DH + lane];
      wvv[u] = WTv[e * DH + lane];
    }
#pragma unroll
    for (int r = 0; r < NQ; r++) {
      float4 xr = ((const float4*)&xL[r][e0])[i4];
      aq[r] += xr.x * wq[0] + xr.y * wq[1] + xr.z * wq[2] + xr.w * wq[3];
      ak[r] += xr.x * wk[0] + xr.y * wk[1] + xr.z * wk[2] + xr.w * wk[3];
      av[r] += xr.x * wvv[0] + xr.y * wvv[1] + xr.z * wvv[2] + xr.w * wvv[3];
    }
  }
#pragma unroll
  for (int r = 0; r < NQ; r++) {
    qP[wv][0][r][lane] = aq[r];
    qP[wv][1][r][lane] = ak[r];
    qP[wv][2][r][lane] = av[r];
  }
  __syncthreads();
  for (int i = tid; i < 3 * NQ * DH; i += NT) {
    int o = i >> 8;
    int rem = i & 255;
    int r = rem >> 6, c = rem & 63;
    float s = 0;
#pragma unroll
    for (int w = 0; w < NW; w++) s += qP[w][o][r][c];
    if (o == 0) q[(size_t)(j0 + r) * DH + c] = s;
    else if (o == 1) kT[(size_t)c * SQ + (j0 + r)] = s;
    else v[(size_t)(j0 + r) * DH + c] = s;
  }
}

// fused: attn(head h) [+ qkv(head h+1) in bf16]
// TI: q/kT/v input elem type (float for h=0, bf16 for h>=1); TV: VT elem type.
// flags bit0: last head -> out = cur/8 ; bit1: compute next-head qkv
template <typename TI, typename TV>
__global__ __launch_bounds__(NT) void fused_kernel(
    float* __restrict__ cur,
    const TI* __restrict__ q, const TI* __restrict__ kT,
    const TI* __restrict__ v, const TV* __restrict__ VT,
    const bf16* __restrict__ WTqn, const bf16* __restrict__ WTkn,
    const bf16* __restrict__ WTvn,
    bf16* __restrict__ qn, bf16* __restrict__ kTn, bf16* __restrict__ vn,
    float* __restrict__ out, int flags) {
  __shared__ float qL[NQ][DH];            // 1 KB
  __shared__ float sL[NQ][W2];            // 4 KB
  __shared__ float pL[NW][NQ][DH];        // 8 KB
  __shared__ float dL[NQ][DH];            // 1 KB
  __shared__ float yL[NQ][DE];            // 8 KB
  __shared__ float qP[NW][3][NQ][DH];     // 24 KB

  int tid = threadIdx.x, lane = tid & 63, wv = tid >> 6;
  int j0 = blockIdx.x * NQ;

  // ---- P0: stage q rows (convert to fp32 in LDS) ----
  if (tid < NQ * DH) ((float*)qL)[tid] = ld(&q[(size_t)j0 * DH + tid]);
  __syncthreads();

  // ---- P1: scores. wave wv covers goff = wv*64 + lane ----
  {
    int goff = wv * 64 + lane;
    if (goff < UW) {
      int g = j0 - CW + goff;
      bool valid = (g >= 0 && g < SQ);
      int gc = valid ? g : 0;
      float acc[NQ] = {0, 0, 0, 0};
#pragma unroll
      for (int d4 = 0; d4 < 16; d4++) {
        float kc[4];
#pragma unroll
        for (int u = 0; u < 4; u++) kc[u] = ld(&kT[(size_t)(d4 * 4 + u) * SQ + gc]);
#pragma unroll
        for (int r = 0; r < NQ; r++) {
          float4 qf = ((const float4*)qL[r])[d4];
          acc[r] += qf.x * kc[0] + qf.y * kc[1] + qf.z * kc[2] + qf.w * kc[3];
        }
      }
#pragma unroll
      for (int r = 0; r < NQ; r++) {
        int p = goff - r;
        if (p >= 0 && p < W2) sL[r][p] = valid ? acc[r] * 0.125f : -INFINITY;
      }
    }
  }
  __syncthreads();

  // ---- P2: softmax, wave per row ----
  if (wv < NQ) {
    int r = wv;
    float m = -INFINITY;
#pragma unroll
    for (int t = 0; t < 4; t++) m = fmaxf(m, sL[r][lane + 64 * t]);
#pragma unroll
    for (int off = 32; off; off >>= 1) m = fmaxf(m, __shfl_xor(m, off));
    float ex[4], ss = 0;
#pragma unroll
    for (int t = 0; t < 4; t++) {
      ex[t] = __expf(sL[r][lane + 64 * t] - m);
      ss += ex[t];
    }
#pragma unroll
    for (int off = 32; off; off >>= 1) ss += __shfl_xor(ss, off);
    float inv = 1.0f / ss;
#pragma unroll
    for (int t = 0; t < 4; t++) sL[r][lane + 64 * t] = ex[t] * inv;
  }
  __syncthreads();

  // ---- P3: PV, 3 chunks of 11 ----
  {
    float dacc[NQ] = {0, 0, 0, 0};
    int gbeg = 33 * wv;
#pragma unroll
    for (int ch = 0; ch < 3; ch++) {
      float vc[11];
#pragma unroll
      for (int i = 0; i < 11; i++) {
        int goff = gbeg + ch * 11 + i;
        int g = j0 - CW + goff;
        int gc = g < 0 ? 0 : (g >= SQ ? SQ - 1 : g);
        vc[i] = ld(&v[(size_t)gc * DH + lane]);
      }
#pragma unroll
      for (int i = 0; i < 11; i++) {
        int goff = gbeg + ch * 11 + i;
        bool act = goff < UW;
#pragma unroll
        for (int r = 0; r < NQ; r++) {
          int p = goff - r;
          float w = (act && p >= 0 && p < W2) ? sL[r][p & 255] : 0.0f;
          dacc[r] += w * vc[i];
        }
      }
    }
#pragma unroll
    for (int r = 0; r < NQ; r++) pL[wv][r][lane] = dacc[r];
  }
  __syncthreads();

  // ---- P4: reduce dL ----
  if (tid < NQ * DH) {
    int r = tid >> 6, c = tid & 63;
    float s = 0;
#pragma unroll
    for (int w = 0; w < NW; w++) s += pL[w][r][c];
    dL[r][c] = s;
  }
  __syncthreads();

  // ---- P5: upproj. wave wv owns e-slice; lane = e-offset ----
  float c8[8];
  {
    int e0 = wv * 64;
    int e = e0 + lane;
    float cr[NQ];
#pragma unroll
    for (int r = 0; r < NQ; r++) cr[r] = cur[(size_t)(j0 + r) * DE + e];
    if (wv < NQ) {
      size_t jrow = (size_t)(j0 + wv) * DE;
#pragma unroll
      for (int t = 0; t < 8; t++) c8[t] = cur[jrow + lane + 64 * t];
    }
    float acc[NQ] = {0, 0, 0, 0};
#pragma unroll
    for (int c4 = 0; c4 < 16; c4++) {
      float wc[4];
#pragma unroll
      for (int u = 0; u < 4; u++) wc[u] = ld(&VT[(size_t)(c4 * 4 + u) * DE + e]);
#pragma unroll
      for (int r = 0; r < NQ; r++) {
        float4 df = ((const float4*)dL[r])[c4];
        acc[r] += df.x * wc[0] + df.y * wc[1] + df.z * wc[2] + df.w * wc[3];
      }
    }
#pragma unroll
    for (int r = 0; r < NQ; r++) yL[r][e] = cr[r] + acc[r];
  }
  __syncthreads();

  // ---- P6: renorm + residual; wave per row ----
  if (wv < NQ) {
    int r = wv;
    size_t jrow = (size_t)(j0 + r) * DE;
    float s = 0;
#pragma unroll
    for (int t = 0; t < 8; t++) s += yL[r][lane + 64 * t];
#pragma unroll
    for (int off = 32; off; off >>= 1) s += __shfl_xor(s, off);
    float inv_m1 = 512.0f / s;
    float y2[8], s2 = 0, s2q = 0;
#pragma unroll
    for (int t = 0; t < 8; t++) {
      y2[t] = yL[r][lane + 64 * t] * inv_m1;
      s2 += y2[t];
      s2q += y2[t] * y2[t];
    }
#pragma unroll
    for (int off = 32; off; off >>= 1) {
      s2 += __shfl_xor(s2, off);
      s2q += __shfl_xor(s2q, off);
    }
    float m2 = s2 * (1.0f / 512.0f);
    float var = (s2q - 512.0f * m2 * m2) * (1.0f / 511.0f);
    float isd = 1.0f / sqrtf(var);
#pragma unroll
    for (int t = 0; t < 8; t++) {
      int e = lane + 64 * t;
      float o = (y2[t] - m2) * isd + m2;
      float nc = c8[t] + o;
      cur[jrow + e] = nc;
      yL[r][e] = nc;
      if (flags & 1) out[jrow + e] = nc * (1.0f / NH);
    }
  }
  __syncthreads();

  // ---- P7: next-head qkv (bf16 weights, fp32 accumulate, bf16 out) ----
  if (flags & 2) {
    float aq[NQ] = {0, 0, 0, 0}, ak[NQ] = {0, 0, 0, 0}, av[NQ] = {0, 0, 0, 0};
    int e0 = wv * 64;
#pragma unroll
    for (int i4 = 0; i4 < 16; i4++) {
      float wq[4], wk[4], wvv[4];
#pragma unroll
      for (int u = 0; u < 4; u++) {
        int e = e0 + i4 * 4 + u;
        wq[u] = ld(&WTqn[e * DH + lane]);
        wk[u] = ld(&WTkn[e * DH + lane]);
        wvv[u] = ld(&WTvn[e * DH + lane]);
      }
#pragma unroll
      for (int r = 0; r < NQ; r++) {
        float4 xr = ((const float4*)&yL[r][e0])[i4];
        aq[r] += xr.x * wq[0] + xr.y * wq[1] + xr.z * wq[2] + xr.w * wq[3];
        ak[r] += xr.x * wk[0] + xr.y * wk[1] + xr.z * wk[2] + xr.w * wk[3];
        av[r] += xr.x * wvv[0] + xr.y * wvv[1] + xr.z * wvv[2] + xr.w * wvv[3];
      }
    }
#pragma unroll
    for (int r = 0; r < NQ; r++) {
      qP[wv][0][r][lane] = aq[r];
      qP[wv][1][r][lane] = ak[r];
      qP[wv][2][r][lane] = av[r];
    }
    __syncthreads();
    for (int i = tid; i < 3 * NQ * DH; i += NT) {
      int o = i >> 8;
      int rem = i & 255;
      int r = rem >> 6, c = rem & 63;
      float s = 0;
#pragma unroll
      for (int w = 0; w < NW; w++) s += qP[w][o][r][c];
      if (o == 0) qn[(size_t)(j0 + r) * DH + c] = __float2bfloat16(s);
      else if (o == 1) kTn[(size_t)c * SQ + (j0 + r)] = __float2bfloat16(s);
      else vn[(size_t)(j0 + r) * DH + c] = __float2bfloat16(s);
    }
  }
}

extern "C" void kernel_launch(void* const* d_in, const int* in_sizes, int n_in,
                              void* d_out, int out_size, void* d_ws, size_t ws_size,
                              hipStream_t stream) {
  const float* x   = (const float*)d_in[0];
  const float* Wq  = (const float*)d_in[1];
  const float* Wk  = (const float*)d_in[2];
  const float* Wvd = (const float*)d_in[3];
  const float* Wvu = (const float*)d_in[4];
  float* out = (float*)d_out;

  float* ws   = (float*)d_ws;
  float* cur  = ws;                     // SQ*DE f32
  float* qA   = cur + SQ * DE;          // SQ*DH f32 (head 0)
  float* kA   = qA + SQ * DH;           // kT layout [DH][SQ]
  float* vA   = kA + SQ * DH;
  float* WT0q = vA + SQ * DH;           // DE*DH f32 (head 0)
  float* WT0k = WT0q + DE * DH;
  float* WT0v = WT0k + DE * DH;
  float* VT0  = WT0v + DE * DH;         // DH*DE f32 (head 0)
  bf16* qB    = (bf16*)(VT0 + DH * DE); // SQ*DH bf16 ping-pong
  bf16* kB    = qB + SQ * DH;
  bf16* vB    = kB + SQ * DH;
  bf16* qC    = vB + SQ * DH;
  bf16* kC    = qC + SQ * DH;
  bf16* vC    = kC + SQ * DH;
  bf16* WTbq  = vC + SQ * DH;           // NH*DE*DH bf16 each
  bf16* WTbk  = WTbq + NH * DE * DH;
  bf16* WTbv  = WTbk + NH * DE * DH;
  bf16* VTb   = WTbv + NH * DE * DH;    // NH*DH*DE bf16

  prep_kernel<<<NH * DE * DH / 256, 256, 0, stream>>>(
      Wq, Wk, Wvd, Wvu, WTbq, WTbk, WTbv, VTb, WT0q, WT0k, WT0v, VT0);
  qkv0_kernel<<<SQ / NQ, NT, 0, stream>>>(x, WT0q, WT0k, WT0v, cur, qA, kA, vA);

  for (int h = 0; h < NH; h++) {
    const size_t won = (size_t)(h + 1 < NH ? h + 1 : 0) * DE * DH;
    int flags = (h == NH - 1 ? 1 : 0) | (h < NH - 1 ? 2 : 0);
    bf16* qo = (h & 1) ? qC : qB;  // h=0 writes B; h=1 reads B writes C; ...
    bf16* ko = (h & 1) ? kC : kB;
    bf16* vo = (h & 1) ? vC : vB;
    if (h == 0) {
      fused_kernel<float, float><<<SQ / NQ, NT, 0, stream>>>(
          cur, qA, kA, vA, VT0,
          WTbq + won, WTbk + won, WTbv + won, qo, ko, vo, out, flags);
    } else {
      const bf16* qi = (h & 1) ? qB : qC;
      const bf16* ki = (h & 1) ? kB : kC;
      const bf16* vi = (h & 1) ? vB : vC;
      fused_kernel<bf16, bf16><<<SQ / NQ, NT, 0, stream>>>(
          cur, qi, ki, vi, VTb + (size_t)h * DH * DE,
          WTbq + won, WTbk + won, WTbv + won, qo, ko, vo, out, flags);
    }
  }
}

// Round 9
// 331.835 us; speedup vs baseline: 1.0215x; 1.0215x over previous
//
#include <hip/hip_runtime.h>
#include <math.h>

#define SQ 2048      // seq len
#define DE 512       // d_embedding
#define DH 64        // d_head
#define CW 128       // half-window
#define W2 256       // window width
#define NH 8         // heads
#define NQ 4         // queries per block
#define UW (W2 + NQ - 1)  // union window width = 259
#define NT 512       // threads per block
#define NW 8         // waves per block
#define NB 512       // persistent grid — needs 2 blocks/CU residency (checked)
#define NG 16        // sync groups
#define GB 32        // blocks per group (= 128 rows)

__device__ __forceinline__ void sig(unsigned* p) {
  __hip_atomic_fetch_add(p, 1u, __ATOMIC_RELEASE, __HIP_MEMORY_SCOPE_AGENT);
}
__device__ __forceinline__ void wait_ge(unsigned* p, unsigned tgt) {
  while (__hip_atomic_load(p, __ATOMIC_ACQUIRE, __HIP_MEMORY_SCOPE_AGENT) < tgt)
    __builtin_amdgcn_s_sleep(4);
}

// prep: WT[h][e][c] = W[h][c][e] (q/k/v), VT[h][c][e] = Wvu[h][e][c]; zero counters
__global__ __launch_bounds__(256) void prep_kernel(
    const float* __restrict__ Wq, const float* __restrict__ Wk,
    const float* __restrict__ Wvd, const float* __restrict__ Wvu,
    float* __restrict__ WTq, float* __restrict__ WTk, float* __restrict__ WTv,
    float* __restrict__ VT, unsigned* __restrict__ cnts) {
  int i = blockIdx.x * 256 + threadIdx.x;
  if (i < NH * DE * DH) {
    int c = i & 63;
    int e = (i >> 6) & 511;
    int h = i >> 15;
    int src = (h * DH + c) * DE + e;
    WTq[i] = Wq[src];
    WTk[i] = Wk[src];
    WTv[i] = Wvd[src];
    VT[(h * DH + c) * DE + e] = Wvu[(h * DE + e) * DH + c];
  }
  if (blockIdx.x == 0 && threadIdx.x < 2 * NH * NG) cnts[threadIdx.x] = 0;
}

// ---------------- fallback path (R6 fp32, proven): qkv0 + per-head fused ----
__global__ __launch_bounds__(NT) void qkv0_kernel(
    const float* __restrict__ x,
    const float* __restrict__ WTq, const float* __restrict__ WTk,
    const float* __restrict__ WTv, float* __restrict__ cur,
    float* __restrict__ q, float* __restrict__ kT, float* __restrict__ v) {
  __shared__ float xL[NQ][DE];
  __shared__ float qP[NW][3][NQ][DH];
  int tid = threadIdx.x, lane = tid & 63, wv = tid >> 6;
  int j0 = blockIdx.x * NQ;

  float4 xv = ((const float4*)(x + (size_t)j0 * DE))[tid];
  ((float4*)xL)[tid] = xv;
  ((float4*)(cur + (size_t)j0 * DE))[tid] = xv;
  __syncthreads();

  float aq[NQ] = {0, 0, 0, 0}, ak[NQ] = {0, 0, 0, 0}, av[NQ] = {0, 0, 0, 0};
  int e0 = wv * 64;
#pragma unroll
  for (int i4 = 0; i4 < 16; i4++) {
    float wq[4], wk[4], wvv[4];
#pragma unroll
    for (int u = 0; u < 4; u++) {
      int e = e0 + i4 * 4 + u;
      wq[u] = WTq[e * DH + lane];
      wk[u] = WTk[e * DH + lane];
      wvv[u] = WTv[e * DH + lane];
    }
#pragma unroll
    for (int r = 0; r < NQ; r++) {
      float4 xr = ((const float4*)&xL[r][e0])[i4];
      aq[r] += xr.x * wq[0] + xr.y * wq[1] + xr.z * wq[2] + xr.w * wq[3];
      ak[r] += xr.x * wk[0] + xr.y * wk[1] + xr.z * wk[2] + xr.w * wk[3];
      av[r] += xr.x * wvv[0] + xr.y * wvv[1] + xr.z * wvv[2] + xr.w * wvv[3];
    }
  }
#pragma unroll
  for (int r = 0; r < NQ; r++) {
    qP[wv][0][r][lane] = aq[r];
    qP[wv][1][r][lane] = ak[r];
    qP[wv][2][r][lane] = av[r];
  }
  __syncthreads();
  for (int i = tid; i < 3 * NQ * DH; i += NT) {
    int o = i >> 8;
    int rem = i & 255;
    int r = rem >> 6, c = rem & 63;
    float s = 0;
#pragma unroll
    for (int w = 0; w < NW; w++) s += qP[w][o][r][c];
    if (o == 0) q[(size_t)(j0 + r) * DH + c] = s;
    else if (o == 1) kT[(size_t)c * SQ + (j0 + r)] = s;
    else v[(size_t)(j0 + r) * DH + c] = s;
  }
}

__global__ __launch_bounds__(NT) void fused_kernel(
    float* __restrict__ cur,
    const float* __restrict__ q, const float* __restrict__ kT,
    const float* __restrict__ v, const float* __restrict__ VT,
    const float* __restrict__ WTqn, const float* __restrict__ WTkn,
    const float* __restrict__ WTvn,
    float* __restrict__ qn, float* __restrict__ kTn, float* __restrict__ vn,
    float* __restrict__ out, int flags) {
  __shared__ float qL[NQ][DH];
  __shared__ float sL[NQ][W2];
  __shared__ float pL[NW][NQ][DH];
  __shared__ float dL[NQ][DH];
  __shared__ float yL[NQ][DE];
  __shared__ float qP[NW][3][NQ][DH];

  int tid = threadIdx.x, lane = tid & 63, wv = tid >> 6;
  int j0 = blockIdx.x * NQ;

  if (tid < NQ * DH) ((float*)qL)[tid] = q[(size_t)j0 * DH + tid];
  __syncthreads();

  {
    int goff = wv * 64 + lane;
    if (goff < UW) {
      int g = j0 - CW + goff;
      bool valid = (g >= 0 && g < SQ);
      int gc = valid ? g : 0;
      float acc[NQ] = {0, 0, 0, 0};
#pragma unroll
      for (int d4 = 0; d4 < 16; d4++) {
        float kc[4];
#pragma unroll
        for (int u = 0; u < 4; u++) kc[u] = kT[(size_t)(d4 * 4 + u) * SQ + gc];
#pragma unroll
        for (int r = 0; r < NQ; r++) {
          float4 qf = ((const float4*)qL[r])[d4];
          acc[r] += qf.x * kc[0] + qf.y * kc[1] + qf.z * kc[2] + qf.w * kc[3];
        }
      }
#pragma unroll
      for (int r = 0; r < NQ; r++) {
        int p = goff - r;
        if (p >= 0 && p < W2) sL[r][p] = valid ? acc[r] * 0.125f : -INFINITY;
      }
    }
  }
  __syncthreads();

  if (wv < NQ) {
    int r = wv;
    float m = -INFINITY;
#pragma unroll
    for (int t = 0; t < 4; t++) m = fmaxf(m, sL[r][lane + 64 * t]);
#pragma unroll
    for (int off = 32; off; off >>= 1) m = fmaxf(m, __shfl_xor(m, off));
    float ex[4], ss = 0;
#pragma unroll
    for (int t = 0; t < 4; t++) {
      ex[t] = __expf(sL[r][lane + 64 * t] - m);
      ss += ex[t];
    }
#pragma unroll
    for (int off = 32; off; off >>= 1) ss += __shfl_xor(ss, off);
    float inv = 1.0f / ss;
#pragma unroll
    for (int t = 0; t < 4; t++) sL[r][lane + 64 * t] = ex[t] * inv;
  }
  __syncthreads();

  {
    float dacc[NQ] = {0, 0, 0, 0};
    int gbeg = 33 * wv;
#pragma unroll
    for (int ch = 0; ch < 3; ch++) {
      float vc[11];
#pragma unroll
      for (int i = 0; i < 11; i++) {
        int goff = gbeg + ch * 11 + i;
        int g = j0 - CW + goff;
        int gc = g < 0 ? 0 : (g >= SQ ? SQ - 1 : g);
        vc[i] = v[(size_t)gc * DH + lane];
      }
#pragma unroll
      for (int i = 0; i < 11; i++) {
        int goff = gbeg + ch * 11 + i;
        bool act = goff < UW;
#pragma unroll
        for (int r = 0; r < NQ; r++) {
          int p = goff - r;
          float w = (act && p >= 0 && p < W2) ? sL[r][p & 255] : 0.0f;
          dacc[r] += w * vc[i];
        }
      }
    }
#pragma unroll
    for (int r = 0; r < NQ; r++) pL[wv][r][lane] = dacc[r];
  }
  __syncthreads();
  if (tid < NQ * DH) {
    int r = tid >> 6, c = tid & 63;
    float s = 0;
#pragma unroll
    for (int w = 0; w < NW; w++) s += pL[w][r][c];
    dL[r][c] = s;
  }
  __syncthreads();

  float c8[8];
  {
    int e0 = wv * 64;
    int e = e0 + lane;
    float cr[NQ];
#pragma unroll
    for (int r = 0; r < NQ; r++) cr[r] = cur[(size_t)(j0 + r) * DE + e];
    if (wv < NQ) {
      size_t jrow = (size_t)(j0 + wv) * DE;
#pragma unroll
      for (int t = 0; t < 8; t++) c8[t] = cur[jrow + lane + 64 * t];
    }
    float acc[NQ] = {0, 0, 0, 0};
#pragma unroll
    for (int c4 = 0; c4 < 16; c4++) {
      float wc[4];
#pragma unroll
      for (int u = 0; u < 4; u++) wc[u] = VT[(size_t)(c4 * 4 + u) * DE + e];
#pragma unroll
      for (int r = 0; r < NQ; r++) {
        float4 df = ((const float4*)dL[r])[c4];
        acc[r] += df.x * wc[0] + df.y * wc[1] + df.z * wc[2] + df.w * wc[3];
      }
    }
#pragma unroll
    for (int r = 0; r < NQ; r++) yL[r][e] = cr[r] + acc[r];
  }
  __syncthreads();

  if (wv < NQ) {
    int r = wv;
    size_t jrow = (size_t)(j0 + r) * DE;
    float s = 0;
#pragma unroll
    for (int t = 0; t < 8; t++) s += yL[r][lane + 64 * t];
#pragma unroll
    for (int off = 32; off; off >>= 1) s += __shfl_xor(s, off);
    float inv_m1 = 512.0f / s;
    float y2[8], s2 = 0, s2q = 0;
#pragma unroll
    for (int t = 0; t < 8; t++) {
      y2[t] = yL[r][lane + 64 * t] * inv_m1;
      s2 += y2[t];
      s2q += y2[t] * y2[t];
    }
#pragma unroll
    for (int off = 32; off; off >>= 1) {
      s2 += __shfl_xor(s2, off);
      s2q += __shfl_xor(s2q, off);
    }
    float m2 = s2 * (1.0f / 512.0f);
    float var = (s2q - 512.0f * m2 * m2) * (1.0f / 511.0f);
    float isd = 1.0f / sqrtf(var);
#pragma unroll
    for (int t = 0; t < 8; t++) {
      int e = lane + 64 * t;
      float o = (y2[t] - m2) * isd + m2;
      float nc = c8[t] + o;
      cur[jrow + e] = nc;
      yL[r][e] = nc;
      if (flags & 1) out[jrow + e] = nc * (1.0f / NH);
    }
  }
  __syncthreads();

  if (flags & 2) {
    float aq[NQ] = {0, 0, 0, 0}, ak[NQ] = {0, 0, 0, 0}, av[NQ] = {0, 0, 0, 0};
    int e0 = wv * 64;
#pragma unroll
    for (int i4 = 0; i4 < 16; i4++) {
      float wq[4], wk[4], wvv[4];
#pragma unroll
      for (int u = 0; u < 4; u++) {
        int e = e0 + i4 * 4 + u;
        wq[u] = WTqn[e * DH + lane];
        wk[u] = WTkn[e * DH + lane];
        wvv[u] = WTvn[e * DH + lane];
      }
#pragma unroll
      for (int r = 0; r < NQ; r++) {
        float4 xr = ((const float4*)&yL[r][e0])[i4];
        aq[r] += xr.x * wq[0] + xr.y * wq[1] + xr.z * wq[2] + xr.w * wq[3];
        ak[r] += xr.x * wk[0] + xr.y * wk[1] + xr.z * wk[2] + xr.w * wk[3];
        av[r] += xr.x * wvv[0] + xr.y * wvv[1] + xr.z * wvv[2] + xr.w * wvv[3];
      }
    }
#pragma unroll
    for (int r = 0; r < NQ; r++) {
      qP[wv][0][r][lane] = aq[r];
      qP[wv][1][r][lane] = ak[r];
      qP[wv][2][r][lane] = av[r];
    }
    __syncthreads();
    for (int i = tid; i < 3 * NQ * DH; i += NT) {
      int o = i >> 8;
      int rem = i & 255;
      int r = rem >> 6, c = rem & 63;
      float s = 0;
#pragma unroll
      for (int w = 0; w < NW; w++) s += qP[w][o][r][c];
      if (o == 0) qn[(size_t)(j0 + r) * DH + c] = s;
      else if (o == 1) kTn[(size_t)c * SQ + (j0 + r)] = s;
      else vn[(size_t)(j0 + r) * DH + c] = s;
    }
  }
}

// ---------------- persistent mega kernel (plain launch; residency checked on host) ----
__global__ __launch_bounds__(NT) void mega_kernel(
    const float* __restrict__ x,
    const float* __restrict__ WTq, const float* __restrict__ WTk,
    const float* __restrict__ WTv, const float* __restrict__ VT,
    float* __restrict__ cur,
    float* __restrict__ qA, float* __restrict__ kA, float* __restrict__ vA,
    float* __restrict__ qB, float* __restrict__ kB, float* __restrict__ vB,
    unsigned* __restrict__ qkvDone, unsigned* __restrict__ attnDone,
    float* __restrict__ out) {
  __shared__ float qL[NQ][DH];
  __shared__ float sL[NQ][W2];
  __shared__ float pL[NW][NQ][DH];
  __shared__ float dL[NQ][DH];
  __shared__ float yL[NQ][DE];
  __shared__ float qP[NW][3][NQ][DH];

  int tid = threadIdx.x, lane = tid & 63, wv = tid >> 6;
  int phys = blockIdx.x;
  int blk = (phys & 7) * 64 + (phys >> 3);  // cluster seq-neighbors per XCD
  int j0 = blk * NQ;
  int g = blk >> 5;

  // ---- Phase X: stage x rows, copy to cur, head-0 qkv ----
  {
    float4 xv = ((const float4*)(x + (size_t)j0 * DE))[tid];
    ((float4*)yL)[tid] = xv;
    ((float4*)(cur + (size_t)j0 * DE))[tid] = xv;
  }
  __syncthreads();
  {
    float aq[NQ] = {0, 0, 0, 0}, ak[NQ] = {0, 0, 0, 0}, av[NQ] = {0, 0, 0, 0};
    int e0 = wv * 64;
#pragma unroll
    for (int i4 = 0; i4 < 16; i4++) {
      float wq[4], wk[4], wvv[4];
#pragma unroll
      for (int u = 0; u < 4; u++) {
        int e = e0 + i4 * 4 + u;
        wq[u] = WTq[e * DH + lane];
        wk[u] = WTk[e * DH + lane];
        wvv[u] = WTv[e * DH + lane];
      }
#pragma unroll
      for (int r = 0; r < NQ; r++) {
        float4 xr = ((const float4*)&yL[r][e0])[i4];
        aq[r] += xr.x * wq[0] + xr.y * wq[1] + xr.z * wq[2] + xr.w * wq[3];
        ak[r] += xr.x * wk[0] + xr.y * wk[1] + xr.z * wk[2] + xr.w * wk[3];
        av[r] += xr.x * wvv[0] + xr.y * wvv[1] + xr.z * wvv[2] + xr.w * wvv[3];
      }
    }
#pragma unroll
    for (int r = 0; r < NQ; r++) {
      qP[wv][0][r][lane] = aq[r];
      qP[wv][1][r][lane] = ak[r];
      qP[wv][2][r][lane] = av[r];
    }
    __syncthreads();
    for (int i = tid; i < 3 * NQ * DH; i += NT) {
      int o = i >> 8;
      int rem = i & 255;
      int r = rem >> 6, c = rem & 63;
      float s = 0;
#pragma unroll
      for (int w = 0; w < NW; w++) s += qP[w][o][r][c];
      if (o == 0) qA[(size_t)(j0 + r) * DH + c] = s;
      else if (o == 1) kA[(size_t)c * SQ + (j0 + r)] = s;
      else vA[(size_t)(j0 + r) * DH + c] = s;
    }
  }
  __syncthreads();  // drains stores before release
  if (tid == 0) sig(&qkvDone[0 * NG + g]);

  for (int h = 0; h < NH; h++) {
    const float* q = (h & 1) ? qB : qA;
    const float* kT = (h & 1) ? kB : kA;
    const float* v = (h & 1) ? vB : vA;
    float* qn = (h & 1) ? qA : qB;
    float* kTn = (h & 1) ? kA : kB;
    float* vn = (h & 1) ? vA : vB;
    const float* VTh = VT + (size_t)h * DH * DE;
    const float* WTqn = WTq + (size_t)(h + 1 < NH ? h + 1 : 0) * DE * DH;
    const float* WTkn = WTk + (size_t)(h + 1 < NH ? h + 1 : 0) * DE * DH;
    const float* WTvn = WTv + (size_t)(h + 1 < NH ? h + 1 : 0) * DE * DH;

    // RAW: neighbor groups have produced head-h qkv
    if (tid < 5) {
      int gg = g - 2 + tid;
      gg = gg < 0 ? 0 : (gg > NG - 1 ? NG - 1 : gg);
      wait_ge(&qkvDone[h * NG + gg], GB);
    }
    __syncthreads();

    if (tid < NQ * DH) ((float*)qL)[tid] = q[(size_t)j0 * DH + tid];
    __syncthreads();

    {
      int goff = wv * 64 + lane;
      if (goff < UW) {
        int gpos = j0 - CW + goff;
        bool valid = (gpos >= 0 && gpos < SQ);
        int gc = valid ? gpos : 0;
        float acc[NQ] = {0, 0, 0, 0};
#pragma unroll
        for (int d4 = 0; d4 < 16; d4++) {
          float kc[4];
#pragma unroll
          for (int u = 0; u < 4; u++) kc[u] = kT[(size_t)(d4 * 4 + u) * SQ + gc];
#pragma unroll
          for (int r = 0; r < NQ; r++) {
            float4 qf = ((const float4*)qL[r])[d4];
            acc[r] += qf.x * kc[0] + qf.y * kc[1] + qf.z * kc[2] + qf.w * kc[3];
          }
        }
#pragma unroll
        for (int r = 0; r < NQ; r++) {
          int p = goff - r;
          if (p >= 0 && p < W2) sL[r][p] = valid ? acc[r] * 0.125f : -INFINITY;
        }
      }
    }
    __syncthreads();

    if (wv < NQ) {
      int r = wv;
      float m = -INFINITY;
#pragma unroll
      for (int t = 0; t < 4; t++) m = fmaxf(m, sL[r][lane + 64 * t]);
#pragma unroll
      for (int off = 32; off; off >>= 1) m = fmaxf(m, __shfl_xor(m, off));
      float ex[4], ss = 0;
#pragma unroll
      for (int t = 0; t < 4; t++) {
        ex[t] = __expf(sL[r][lane + 64 * t] - m);
        ss += ex[t];
      }
#pragma unroll
      for (int off = 32; off; off >>= 1) ss += __shfl_xor(ss, off);
      float inv = 1.0f / ss;
#pragma unroll
      for (int t = 0; t < 4; t++) sL[r][lane + 64 * t] = ex[t] * inv;
    }
    __syncthreads();

    {
      float dacc[NQ] = {0, 0, 0, 0};
      int gbeg = 33 * wv;
#pragma unroll
      for (int ch = 0; ch < 3; ch++) {
        float vc[11];
#pragma unroll
        for (int i = 0; i < 11; i++) {
          int goff = gbeg + ch * 11 + i;
          int gpos = j0 - CW + goff;
          int gc = gpos < 0 ? 0 : (gpos >= SQ ? SQ - 1 : gpos);
          vc[i] = v[(size_t)gc * DH + lane];
        }
#pragma unroll
        for (int i = 0; i < 11; i++) {
          int goff = gbeg + ch * 11 + i;
          bool act = goff < UW;
#pragma unroll
          for (int r = 0; r < NQ; r++) {
            int p = goff - r;
            float w = (act && p >= 0 && p < W2) ? sL[r][p & 255] : 0.0f;
            dacc[r] += w * vc[i];
          }
        }
      }
#pragma unroll
      for (int r = 0; r < NQ; r++) pL[wv][r][lane] = dacc[r];
    }
    __syncthreads();
    // last read of q/kT/v for head h done -> release WAR
    if (tid == 0) sig(&attnDone[h * NG + g]);

    if (tid < NQ * DH) {
      int r = tid >> 6, c = tid & 63;
      float s = 0;
#pragma unroll
      for (int w = 0; w < NW; w++) s += pL[w][r][c];
      dL[r][c] = s;
    }
    __syncthreads();

    float c8[8];
    {
      int e0 = wv * 64;
      int e = e0 + lane;
      float cr[NQ];
#pragma unroll
      for (int r = 0; r < NQ; r++) cr[r] = cur[(size_t)(j0 + r) * DE + e];
      if (wv < NQ) {
        size_t jrow = (size_t)(j0 + wv) * DE;
#pragma unroll
        for (int t = 0; t < 8; t++) c8[t] = cur[jrow + lane + 64 * t];
      }
      float acc[NQ] = {0, 0, 0, 0};
#pragma unroll
      for (int c4 = 0; c4 < 16; c4++) {
        float wc[4];
#pragma unroll
        for (int u = 0; u < 4; u++) wc[u] = VTh[(size_t)(c4 * 4 + u) * DE + e];
#pragma unroll
        for (int r = 0; r < NQ; r++) {
          float4 df = ((const float4*)dL[r])[c4];
          acc[r] += df.x * wc[0] + df.y * wc[1] + df.z * wc[2] + df.w * wc[3];
        }
      }
#pragma unroll
      for (int r = 0; r < NQ; r++) yL[r][e] = cr[r] + acc[r];
    }
    __syncthreads();

    if (wv < NQ) {
      int r = wv;
      size_t jrow = (size_t)(j0 + r) * DE;
      float s = 0;
#pragma unroll
      for (int t = 0; t < 8; t++) s += yL[r][lane + 64 * t];
#pragma unroll
      for (int off = 32; off; off >>= 1) s += __shfl_xor(s, off);
      float inv_m1 = 512.0f / s;
      float y2[8], s2 = 0, s2q = 0;
#pragma unroll
      for (int t = 0; t < 8; t++) {
        y2[t] = yL[r][lane + 64 * t] * inv_m1;
        s2 += y2[t];
        s2q += y2[t] * y2[t];
      }
#pragma unroll
      for (int off = 32; off; off >>= 1) {
        s2 += __shfl_xor(s2, off);
        s2q += __shfl_xor(s2q, off);
      }
      float m2 = s2 * (1.0f / 512.0f);
      float var = (s2q - 512.0f * m2 * m2) * (1.0f / 511.0f);
      float isd = 1.0f / sqrtf(var);
#pragma unroll
      for (int t = 0; t < 8; t++) {
        int e = lane + 64 * t;
        float o = (y2[t] - m2) * isd + m2;
        float nc = c8[t] + o;
        cur[jrow + e] = nc;
        yL[r][e] = nc;
        if (h == NH - 1) out[jrow + e] = nc * (1.0f / NH);
      }
    }
    __syncthreads();

    if (h < NH - 1) {
      if (h >= 1) {  // WAR: neighbors done reading the parity buffer we write
        if (tid < 5) {
          int gg = g - 2 + tid;
          gg = gg < 0 ? 0 : (gg > NG - 1 ? NG - 1 : gg);
          wait_ge(&attnDone[(h - 1) * NG + gg], GB);
        }
        __syncthreads();
      }
      float aq[NQ] = {0, 0, 0, 0}, ak[NQ] = {0, 0, 0, 0}, av[NQ] = {0, 0, 0, 0};
      int e0 = wv * 64;
#pragma unroll
      for (int i4 = 0; i4 < 16; i4++) {
        float wq[4], wk[4], wvv[4];
#pragma unroll
        for (int u = 0; u < 4; u++) {
          int e = e0 + i4 * 4 + u;
          wq[u] = WTqn[e * DH + lane];
          wk[u] = WTkn[e * DH + lane];
          wvv[u] = WTvn[e * DH + lane];
        }
#pragma unroll
        for (int r = 0; r < NQ; r++) {
          float4 xr = ((const float4*)&yL[r][e0])[i4];
          aq[r] += xr.x * wq[0] + xr.y * wq[1] + xr.z * wq[2] + xr.w * wq[3];
          ak[r] += xr.x * wk[0] + xr.y * wk[1] + xr.z * wk[2] + xr.w * wk[3];
          av[r] += xr.x * wvv[0] + xr.y * wvv[1] + xr.z * wvv[2] + xr.w * wvv[3];
        }
      }
#pragma unroll
      for (int r = 0; r < NQ; r++) {
        qP[wv][0][r][lane] = aq[r];
        qP[wv][1][r][lane] = ak[r];
        qP[wv][2][r][lane] = av[r];
      }
      __syncthreads();
      for (int i = tid; i < 3 * NQ * DH; i += NT) {
        int o = i >> 8;
        int rem = i & 255;
        int r = rem >> 6, c = rem & 63;
        float s = 0;
#pragma unroll
        for (int w = 0; w < NW; w++) s += qP[w][o][r][c];
        if (o == 0) qn[(size_t)(j0 + r) * DH + c] = s;
        else if (o == 1) kTn[(size_t)c * SQ + (j0 + r)] = s;
        else vn[(size_t)(j0 + r) * DH + c] = s;
      }
      __syncthreads();  // store drain before release
      if (tid == 0) sig(&qkvDone[(h + 1) * NG + g]);
    }
  }
}

extern "C" void kernel_launch(void* const* d_in, const int* in_sizes, int n_in,
                              void* d_out, int out_size, void* d_ws, size_t ws_size,
                              hipStream_t stream) {
  const float* x   = (const float*)d_in[0];
  const float* Wq  = (const float*)d_in[1];
  const float* Wk  = (const float*)d_in[2];
  const float* Wvd = (const float*)d_in[3];
  const float* Wvu = (const float*)d_in[4];
  float* out = (float*)d_out;

  float* ws  = (float*)d_ws;
  float* cur = ws;                    // SQ*DE
  float* qA  = cur + SQ * DE;         // SQ*DH each; k in kT layout [DH][SQ]
  float* kA  = qA + SQ * DH;
  float* vA  = kA + SQ * DH;
  float* qB  = vA + SQ * DH;
  float* kB  = qB + SQ * DH;
  float* vB  = kB + SQ * DH;
  float* WTq = vB + SQ * DH;          // NH*DE*DH each
  float* WTk = WTq + NH * DE * DH;
  float* WTv = WTk + NH * DE * DH;
  float* VT  = WTv + NH * DE * DH;    // NH*DH*DE
  unsigned* cnts = (unsigned*)(VT + NH * DH * DE);
  unsigned* qkvDone = cnts;
  unsigned* attnDone = cnts + NH * NG;

  prep_kernel<<<NH * DE * DH / 256, 256, 0, stream>>>(Wq, Wk, Wvd, Wvu,
                                                      WTq, WTk, WTv, VT, cnts);

  // Residency check (host-side, deterministic, capture-safe): the flag-sync
  // pipeline is deadlock-free only if all NB blocks are co-resident.
  int maxBlocksPerCU = 0;
  hipError_t qe = hipOccupancyMaxActiveBlocksPerMultiprocessor(
      &maxBlocksPerCU, (const void*)mega_kernel, NT, 0);
  bool coop_ok = (qe == hipSuccess) && (maxBlocksPerCU * 256 >= NB);

  if (coop_ok) {
    mega_kernel<<<NB, NT, 0, stream>>>(x, WTq, WTk, WTv, VT, cur,
                                       qA, kA, vA, qB, kB, vB,
                                       qkvDone, attnDone, out);
  } else {
    // fallback: proven per-head sequence (R6)
    qkv0_kernel<<<SQ / NQ, NT, 0, stream>>>(x, WTq, WTk, WTv, cur, qA, kA, vA);
    for (int h = 0; h < NH; h++) {
      const float* qi = (h & 1) ? qB : qA;
      const float* ki = (h & 1) ? kB : kA;
      const float* vi = (h & 1) ? vB : vA;
      float* qo = (h & 1) ? qA : qB;
      float* ko = (h & 1) ? kA : kB;
      float* vo = (h & 1) ? vA : vB;
      const size_t won = (size_t)(h + 1 < NH ? h + 1 : 0) * DE * DH;
      int flags = (h == NH - 1 ? 1 : 0) | (h < NH - 1 ? 2 : 0);
      fused_kernel<<<SQ / NQ, NT, 0, stream>>>(
          cur, qi, ki, vi, VT + (size_t)h * DH * DE,
          WTq + won, WTk + won, WTv + won, qo, ko, vo, out, flags);
    }
  }
}

// Round 10
// 314.482 us; speedup vs baseline: 1.0778x; 1.0552x over previous
//
#include <hip/hip_runtime.h>
#include <math.h>

#define SQ 2048      // seq len
#define DE 512       // d_embedding
#define DH 64        // d_head
#define CW 128       // half-window
#define W2 256       // window width
#define NH 8         // heads
#define NQ 4         // queries per block
#define UW (W2 + NQ - 1)  // union window width = 259
#define NT 512       // threads per block
#define NW 8         // waves per block

// prep: packed-float4 weight layouts.
// WT4[h][e/4][c][u] (u=e%4): lane c loads float4 covering 4 consecutive e.
// VT4[h][c/4][e][u] (u=c%4): lane e loads float4 covering 4 consecutive c.
__global__ __launch_bounds__(256) void prep_kernel(
    const float* __restrict__ Wq, const float* __restrict__ Wk,
    const float* __restrict__ Wvd, const float* __restrict__ Wvu,
    float* __restrict__ WT4q, float* __restrict__ WT4k, float* __restrict__ WT4v,
    float* __restrict__ VT4) {
  int i = blockIdx.x * 256 + threadIdx.x;
  if (i < NH * DE * DH) {
    int c = i & 63;
    int e = (i >> 6) & 511;
    int h = i >> 15;
    int src = (h * DH + c) * DE + e;
    int w4i = ((h * 128 + (e >> 2)) * 64 + c) * 4 + (e & 3);
    WT4q[w4i] = Wq[src];
    WT4k[w4i] = Wk[src];
    WT4v[w4i] = Wvd[src];
    int v4i = ((h * 16 + (c >> 2)) * 512 + e) * 4 + (c & 3);
    VT4[v4i] = Wvu[(h * DE + e) * DH + c];
  }
}

// qkv0: x -> cur copy + q/kT/v for head 0 (float4 weight loads)
__global__ __launch_bounds__(NT) void qkv0_kernel(
    const float* __restrict__ x,
    const float4* __restrict__ Wq4, const float4* __restrict__ Wk4,
    const float4* __restrict__ Wv4, float* __restrict__ cur,
    float* __restrict__ q, float* __restrict__ kT, float* __restrict__ v) {
  __shared__ float xL[NQ][DE];
  __shared__ float qP[NW][3][NQ][DH];
  int tid = threadIdx.x, lane = tid & 63, wv = tid >> 6;
  int j0 = blockIdx.x * NQ;

  float4 xv = ((const float4*)(x + (size_t)j0 * DE))[tid];
  ((float4*)xL)[tid] = xv;
  ((float4*)(cur + (size_t)j0 * DE))[tid] = xv;
  __syncthreads();

  float aq[NQ] = {0, 0, 0, 0}, ak[NQ] = {0, 0, 0, 0}, av[NQ] = {0, 0, 0, 0};
  int e0 = wv * 64;
#pragma unroll
  for (int i4 = 0; i4 < 16; i4++) {
    int widx = (wv * 16 + i4) * 64 + lane;
    float4 wq4 = Wq4[widx];
    float4 wk4 = Wk4[widx];
    float4 wv4 = Wv4[widx];
#pragma unroll
    for (int r = 0; r < NQ; r++) {
      float4 xr = ((const float4*)&xL[r][e0])[i4];
      aq[r] += xr.x * wq4.x + xr.y * wq4.y + xr.z * wq4.z + xr.w * wq4.w;
      ak[r] += xr.x * wk4.x + xr.y * wk4.y + xr.z * wk4.z + xr.w * wk4.w;
      av[r] += xr.x * wv4.x + xr.y * wv4.y + xr.z * wv4.z + xr.w * wv4.w;
    }
  }
#pragma unroll
  for (int r = 0; r < NQ; r++) {
    qP[wv][0][r][lane] = aq[r];
    qP[wv][1][r][lane] = ak[r];
    qP[wv][2][r][lane] = av[r];
  }
  __syncthreads();
  for (int i = tid; i < 3 * NQ * DH; i += NT) {
    int o = i >> 8;
    int rem = i & 255;
    int r = rem >> 6, c = rem & 63;
    float s = 0;
#pragma unroll
    for (int w = 0; w < NW; w++) s += qP[w][o][r][c];
    if (o == 0) q[(size_t)(j0 + r) * DH + c] = s;
    else if (o == 1) kT[(size_t)c * SQ + (j0 + r)] = s;
    else v[(size_t)(j0 + r) * DH + c] = s;
  }
}

// fused: attn(head h) [+ qkv(head h+1)]
// flags bit0: last head -> out = cur/8 ; bit1: compute next-head qkv
__global__ __launch_bounds__(NT) void fused_kernel(
    float* __restrict__ cur,
    const float* __restrict__ q, const float* __restrict__ kT,
    const float* __restrict__ v, const float4* __restrict__ VT4h,
    const float4* __restrict__ Wq4n, const float4* __restrict__ Wk4n,
    const float4* __restrict__ Wv4n,
    float* __restrict__ qn, float* __restrict__ kTn, float* __restrict__ vn,
    float* __restrict__ out, int flags) {
  __shared__ float qL[NQ][DH];
  __shared__ float sL[NQ][W2];
  __shared__ float pL[NW][NQ][DH];
  __shared__ float dL[NQ][DH];
  __shared__ float yL[NQ][DE];
  __shared__ float qP[NW][3][NQ][DH];

  int tid = threadIdx.x, lane = tid & 63, wv = tid >> 6;
  int j0 = blockIdx.x * NQ;

  // P0: stage q rows
  if (tid < NQ * DH) ((float*)qL)[tid] = q[(size_t)j0 * DH + tid];
  __syncthreads();

  // P1: scores; 8 kT loads in flight per chunk
  {
    int goff = wv * 64 + lane;
    if (goff < UW) {
      int g = j0 - CW + goff;
      bool valid = (g >= 0 && g < SQ);
      int gc = valid ? g : 0;
      float acc[NQ] = {0, 0, 0, 0};
#pragma unroll
      for (int d8 = 0; d8 < 8; d8++) {
        float kc[8];
#pragma unroll
        for (int u = 0; u < 8; u++) kc[u] = kT[(size_t)(d8 * 8 + u) * SQ + gc];
#pragma unroll
        for (int r = 0; r < NQ; r++) {
          float4 q0 = ((const float4*)qL[r])[2 * d8];
          float4 q1 = ((const float4*)qL[r])[2 * d8 + 1];
          acc[r] += q0.x * kc[0] + q0.y * kc[1] + q0.z * kc[2] + q0.w * kc[3] +
                    q1.x * kc[4] + q1.y * kc[5] + q1.z * kc[6] + q1.w * kc[7];
        }
      }
#pragma unroll
      for (int r = 0; r < NQ; r++) {
        int p = goff - r;
        if (p >= 0 && p < W2) sL[r][p] = valid ? acc[r] * 0.125f : -INFINITY;
      }
    }
  }
  __syncthreads();

  // P2: softmax, wave per row
  if (wv < NQ) {
    int r = wv;
    float m = -INFINITY;
#pragma unroll
    for (int t = 0; t < 4; t++) m = fmaxf(m, sL[r][lane + 64 * t]);
#pragma unroll
    for (int off = 32; off; off >>= 1) m = fmaxf(m, __shfl_xor(m, off));
    float ex[4], ss = 0;
#pragma unroll
    for (int t = 0; t < 4; t++) {
      ex[t] = __expf(sL[r][lane + 64 * t] - m);
      ss += ex[t];
    }
#pragma unroll
    for (int off = 32; off; off >>= 1) ss += __shfl_xor(ss, off);
    float inv = 1.0f / ss;
#pragma unroll
    for (int t = 0; t < 4; t++) sL[r][lane + 64 * t] = ex[t] * inv;
  }
  __syncthreads();

  // P3: PV, 3 chunks of 11
  {
    float dacc[NQ] = {0, 0, 0, 0};
    int gbeg = 33 * wv;
#pragma unroll
    for (int ch = 0; ch < 3; ch++) {
      float vc[11];
#pragma unroll
      for (int i = 0; i < 11; i++) {
        int goff = gbeg + ch * 11 + i;
        int g = j0 - CW + goff;
        int gc = g < 0 ? 0 : (g >= SQ ? SQ - 1 : g);
        vc[i] = v[(size_t)gc * DH + lane];
      }
#pragma unroll
      for (int i = 0; i < 11; i++) {
        int goff = gbeg + ch * 11 + i;
        bool act = goff < UW;
#pragma unroll
        for (int r = 0; r < NQ; r++) {
          int p = goff - r;
          float w = (act && p >= 0 && p < W2) ? sL[r][p & 255] : 0.0f;
          dacc[r] += w * vc[i];
        }
      }
    }
#pragma unroll
    for (int r = 0; r < NQ; r++) pL[wv][r][lane] = dacc[r];
  }
  __syncthreads();
  if (tid < NQ * DH) {
    int r = tid >> 6, c = tid & 63;
    float s = 0;
#pragma unroll
    for (int w = 0; w < NW; w++) s += pL[w][r][c];
    dL[r][c] = s;
  }
  __syncthreads();

  // P5: upproj with float4 VT loads; thread owns e = tid
  float c8[8];
  {
    int e = tid;
    float cr[NQ];
#pragma unroll
    for (int r = 0; r < NQ; r++) cr[r] = cur[(size_t)(j0 + r) * DE + e];
    if (wv < NQ) {
      size_t jrow = (size_t)(j0 + wv) * DE;
#pragma unroll
      for (int t = 0; t < 8; t++) c8[t] = cur[jrow + lane + 64 * t];
    }
    float acc[NQ] = {0, 0, 0, 0};
#pragma unroll
    for (int c4 = 0; c4 < 16; c4++) {
      float4 wc4 = VT4h[c4 * 512 + e];
#pragma unroll
      for (int r = 0; r < NQ; r++) {
        float4 df = ((const float4*)dL[r])[c4];
        acc[r] += df.x * wc4.x + df.y * wc4.y + df.z * wc4.z + df.w * wc4.w;
      }
    }
#pragma unroll
    for (int r = 0; r < NQ; r++) yL[r][e] = cr[r] + acc[r];
  }
  __syncthreads();

  // P6: renorm + residual; wave per row
  if (wv < NQ) {
    int r = wv;
    size_t jrow = (size_t)(j0 + r) * DE;
    float s = 0;
#pragma unroll
    for (int t = 0; t < 8; t++) s += yL[r][lane + 64 * t];
#pragma unroll
    for (int off = 32; off; off >>= 1) s += __shfl_xor(s, off);
    float inv_m1 = 512.0f / s;
    float y2[8], s2 = 0, s2q = 0;
#pragma unroll
    for (int t = 0; t < 8; t++) {
      y2[t] = yL[r][lane + 64 * t] * inv_m1;
      s2 += y2[t];
      s2q += y2[t] * y2[t];
    }
#pragma unroll
    for (int off = 32; off; off >>= 1) {
      s2 += __shfl_xor(s2, off);
      s2q += __shfl_xor(s2q, off);
    }
    float m2 = s2 * (1.0f / 512.0f);
    float var = (s2q - 512.0f * m2 * m2) * (1.0f / 511.0f);
    float isd = 1.0f / sqrtf(var);
#pragma unroll
    for (int t = 0; t < 8; t++) {
      int e = lane + 64 * t;
      float o = (y2[t] - m2) * isd + m2;
      float nc = c8[t] + o;
      cur[jrow + e] = nc;
      yL[r][e] = nc;
      if (flags & 1) out[jrow + e] = nc * (1.0f / NH);
    }
  }
  __syncthreads();

  // P7: next-head qkv with float4 weight loads; wave e-slice
  if (flags & 2) {
    float aq[NQ] = {0, 0, 0, 0}, ak[NQ] = {0, 0, 0, 0}, av[NQ] = {0, 0, 0, 0};
    int e0 = wv * 64;
#pragma unroll
    for (int i4 = 0; i4 < 16; i4++) {
      int widx = (wv * 16 + i4) * 64 + lane;
      float4 wq4 = Wq4n[widx];
      float4 wk4 = Wk4n[widx];
      float4 wv4 = Wv4n[widx];
#pragma unroll
      for (int r = 0; r < NQ; r++) {
        float4 xr = ((const float4*)&yL[r][e0])[i4];
        aq[r] += xr.x * wq4.x + xr.y * wq4.y + xr.z * wq4.z + xr.w * wq4.w;
        ak[r] += xr.x * wk4.x + xr.y * wk4.y + xr.z * wk4.z + xr.w * wk4.w;
        av[r] += xr.x * wv4.x + xr.y * wv4.y + xr.z * wv4.z + xr.w * wv4.w;
      }
    }
#pragma unroll
    for (int r = 0; r < NQ; r++) {
      qP[wv][0][r][lane] = aq[r];
      qP[wv][1][r][lane] = ak[r];
      qP[wv][2][r][lane] = av[r];
    }
    __syncthreads();
    for (int i = tid; i < 3 * NQ * DH; i += NT) {
      int o = i >> 8;
      int rem = i & 255;
      int r = rem >> 6, c = rem & 63;
      float s = 0;
#pragma unroll
      for (int w = 0; w < NW; w++) s += qP[w][o][r][c];
      if (o == 0) qn[(size_t)(j0 + r) * DH + c] = s;
      else if (o == 1) kTn[(size_t)c * SQ + (j0 + r)] = s;
      else vn[(size_t)(j0 + r) * DH + c] = s;
    }
  }
}

extern "C" void kernel_launch(void* const* d_in, const int* in_sizes, int n_in,
                              void* d_out, int out_size, void* d_ws, size_t ws_size,
                              hipStream_t stream) {
  const float* x   = (const float*)d_in[0];
  const float* Wq  = (const float*)d_in[1];
  const float* Wk  = (const float*)d_in[2];
  const float* Wvd = (const float*)d_in[3];
  const float* Wvu = (const float*)d_in[4];
  float* out = (float*)d_out;

  float* ws  = (float*)d_ws;
  float* cur = ws;                    // SQ*DE
  float* qA  = cur + SQ * DE;         // SQ*DH each; k in kT layout [DH][SQ]
  float* kA  = qA + SQ * DH;
  float* vA  = kA + SQ * DH;
  float* qB  = vA + SQ * DH;
  float* kB  = qB + SQ * DH;
  float* vB  = kB + SQ * DH;
  float* WTq = vB + SQ * DH;          // NH*DE*DH each (packed float4 layout)
  float* WTk = WTq + NH * DE * DH;
  float* WTv = WTk + NH * DE * DH;
  float* VT  = WTv + NH * DE * DH;    // NH*DH*DE (packed float4 layout)

  prep_kernel<<<NH * DE * DH / 256, 256, 0, stream>>>(Wq, Wk, Wvd, Wvu,
                                                      WTq, WTk, WTv, VT);
  qkv0_kernel<<<SQ / NQ, NT, 0, stream>>>(
      x, (const float4*)WTq, (const float4*)WTk, (const float4*)WTv,
      cur, qA, kA, vA);

  for (int h = 0; h < NH; h++) {
    const float* qi = (h & 1) ? qB : qA;
    const float* ki = (h & 1) ? kB : kA;
    const float* vi = (h & 1) ? vB : vA;
    float* qo = (h & 1) ? qA : qB;
    float* ko = (h & 1) ? kA : kB;
    float* vo = (h & 1) ? vA : vB;
    const size_t won = (size_t)(h + 1 < NH ? h + 1 : 0) * DE * DH / 4;
    int flags = (h == NH - 1 ? 1 : 0) | (h < NH - 1 ? 2 : 0);
    fused_kernel<<<SQ / NQ, NT, 0, stream>>>(
        cur, qi, ki, vi, (const float4*)VT + (size_t)h * DH * DE / 4,
        (const float4*)WTq + won, (const float4*)WTk + won,
        (const float4*)WTv + won, qo, ko, vo, out, flags);
  }
}